// Round 1
// baseline (454.338 us; speedup 1.0000x reference)
//
#include <hip/hip_runtime.h>
#include <hip/hip_bf16.h>

#define GL2L16(gp, lp) __builtin_amdgcn_global_load_lds(                      \
    (const __attribute__((address_space(1))) void*)(gp),                      \
    (__attribute__((address_space(3))) void*)(lp), 16, 0, 0)

constexpr int H    = 4096;
constexpr int E    = 64;
constexpr int NTOK = 16384;   // 4 * 4096
constexpr int TB   = 32;      // tokens per block (router)
constexpr int KC   = 64;      // h-chunk
constexpr int NB2  = 128;     // blocks for sort kernels (32768 / 256)

// ---------------- kernel 0: gate transpose  gT[h][e] = gw[e][h] -------------
__global__ __launch_bounds__(256) void transpose_gate_k(
    const float* __restrict__ gw, float* __restrict__ gT) {
  int idx = blockIdx.x * 256 + threadIdx.x;   // 0 .. 262143, coalesced writes
  int h = idx >> 6, e = idx & 63;
  gT[idx] = gw[e * H + h];
}

// ---------------- kernel 1: logits GEMM + softmax + top2 -------------------
// block: 256 thr (4 waves). thread tile: 2 tokens x 4 experts.
// te = tid&15 (expert group, e0=4*te), tt = tid>>4 (token group, t=2*tt+i)
__global__ __launch_bounds__(256) void router_k(
    const float* __restrict__ hidden, const float* __restrict__ gT,
    float* __restrict__ out_w, float* __restrict__ out_idx,
    int* __restrict__ flatE) {
  __shared__ float As[TB * KC];   // [t][h]  8 KB, linear (global_load_lds dest)
  __shared__ float Gs[KC * E];    // [h][e] 16 KB, linear

  const int tid = threadIdx.x;
  const int te = tid & 15, tt = tid >> 4;
  const int t0 = blockIdx.x * TB;
  const float* hblock = hidden + (size_t)t0 * H;

  float acc[2][4] = {{0.f, 0.f, 0.f, 0.f}, {0.f, 0.f, 0.f, 0.f}};

  for (int hc = 0; hc < H; hc += KC) {
    __syncthreads();  // previous compute done before LDS overwrite
    // stage A: 32x64 f32 = 8KB -> 2 issues of 256 lanes x 16B
#pragma unroll
    for (int r = 0; r < 2; ++r) {
      int lid = r * 256 + tid;              // 0..511
      int t = lid >> 4, h4 = (lid & 15) * 4;
      GL2L16(hblock + t * H + hc + h4, &As[lid * 4]);
    }
    // stage G: 64x64 f32 = 16KB contiguous in gT -> 4 issues
    const float* gsrc = gT + hc * E;
#pragma unroll
    for (int r = 0; r < 4; ++r) {
      int lid = r * 256 + tid;
      GL2L16(gsrc + lid * 4, &Gs[lid * 4]);
    }
    __syncthreads();  // compiler drains vmcnt(0) before s_barrier

#pragma unroll
    for (int kk = 0; kk < KC; kk += 4) {
      float a[2][4], g[4][4];
      *(float4*)&a[0][0] = *(const float4*)&As[(2 * tt + 0) * KC + kk];
      *(float4*)&a[1][0] = *(const float4*)&As[(2 * tt + 1) * KC + kk];
#pragma unroll
      for (int k = 0; k < 4; ++k)
        *(float4*)&g[k][0] = *(const float4*)&Gs[(kk + k) * E + 4 * te];
#pragma unroll
      for (int i = 0; i < 2; ++i)
#pragma unroll
        for (int j = 0; j < 4; ++j)
#pragma unroll
          for (int k = 0; k < 4; ++k)
            acc[i][j] = fmaf(a[i][k], g[k][j], acc[i][j]);
    }
  }

  // ---- per-token softmax + top2 (64 experts spread over 16 lanes x 4) ----
#pragma unroll
  for (int i = 0; i < 2; ++i) {
    float v1 = -3.0e38f, v2 = -3.0e38f;
    int e1 = 0, e2 = 0;
#pragma unroll
    for (int j = 0; j < 4; ++j) {
      float v = acc[i][j];
      int e = 4 * te + j;
      if (v > v1 || (v == v1 && e < e1)) {
        v2 = v1; e2 = e1; v1 = v; e1 = e;
      } else if (v > v2 || (v == v2 && e < e2)) {
        v2 = v; e2 = e;
      }
    }
#pragma unroll
    for (int m = 1; m <= 8; m <<= 1) {
      float ov1 = __shfl_xor(v1, m); int oe1 = __shfl_xor(e1, m);
      float ov2 = __shfl_xor(v2, m); int oe2 = __shfl_xor(e2, m);
      bool aFirst = (v1 > ov1) || (v1 == ov1 && e1 < oe1);
      float w1v = aFirst ? v1 : ov1;  int w1e = aFirst ? e1 : oe1;
      float c1  = aFirst ? ov1 : v1;  int c1e = aFirst ? oe1 : e1;  // loser of firsts
      float c2  = aFirst ? v2 : ov2;  int c2e = aFirst ? e2 : oe2;  // winner's 2nd
      bool s = (c2 > c1) || (c2 == c1 && c2e < c1e);
      v1 = w1v; e1 = w1e;
      v2 = s ? c2 : c1; e2 = s ? c2e : c1e;
    }
    // softmax denominator over all 64 experts (max == v1)
    float sum = 0.f;
#pragma unroll
    for (int j = 0; j < 4; ++j) sum += __expf(acc[i][j] - v1);
#pragma unroll
    for (int m = 1; m <= 8; m <<= 1) sum += __shfl_xor(sum, m);

    float p1 = 1.0f / sum;               // exp(0)/sum
    float p2 = __expf(v2 - v1) / sum;
    float inv = 1.0f / (p1 + p2 + 1e-8f);
    float w1 = p1 * inv, w2 = p2 * inv;

    if (te == 0) {
      int t = t0 + 2 * tt + i;
      out_w[2 * t]       = w1;
      out_w[2 * t + 1]   = w2;
      out_idx[2 * t]     = (float)e1;
      out_idx[2 * t + 1] = (float)e2;
      flatE[2 * t]       = e1;
      flatE[2 * t + 1]   = e2;
    }
  }
}

// ---------------- kernel 2a: per-block histogram + stable in-block rank ----
__global__ __launch_bounds__(256) void hist_rank_k(
    const int* __restrict__ flatE, int* __restrict__ blockCounts,
    int* __restrict__ rankInBlock) {
  __shared__ int waveCnt[4][64];
  const int tid = threadIdx.x, blk = blockIdx.x;
  const int i = blk * 256 + tid;
  const int key = flatE[i];
  const int lane = tid & 63, w = tid >> 6;
  const unsigned long long below = (1ull << lane) - 1ull;

  int rankWave = 0, cntMyLane = 0;
  for (int e = 0; e < 64; ++e) {
    unsigned long long m = __ballot(key == e);
    if (e == key)  rankWave  = __popcll(m & below);
    if (e == lane) cntMyLane = __popcll(m);
  }
  waveCnt[w][lane] = cntMyLane;
  __syncthreads();

  int pre = 0;
  for (int w2 = 0; w2 < w; ++w2) pre += waveCnt[w2][key];
  rankInBlock[i] = pre + rankWave;

  if (tid < 64) {
    int tot = waveCnt[0][tid] + waveCnt[1][tid] + waveCnt[2][tid] + waveCnt[3][tid];
    blockCounts[blk * 64 + tid] = tot;
  }
}

// ---------------- kernel 2b: offsets (1 wave) ------------------------------
__global__ void offsets_k(const int* __restrict__ blockCounts,
                          int* __restrict__ offTable,
                          float* __restrict__ out_off,
                          float* __restrict__ out_losses) {
  const int e = threadIdx.x;  // 0..63, single wave
  int run = 0;
  for (int b = 0; b < NB2; ++b) {
    offTable[e * NB2 + b] = run;          // exclusive within expert
    run += blockCounts[b * 64 + e];
  }
  const int total = run;
  int inc = total;                         // inclusive scan across experts
  for (int d = 1; d < 64; d <<= 1) {
    int v = __shfl_up(inc, d);
    if (e >= d) inc += v;
  }
  out_off[e] = (float)inc;                 // expert_offsets = inclusive cumsum
  const int base = inc - total;            // exclusive global base
  for (int b = 0; b < NB2; ++b) offTable[e * NB2 + b] += base;
  if (e == 0) { out_losses[0] = 0.f; out_losses[1] = 0.f; }
}

// ---------------- kernel 2c: stable scatter --------------------------------
__global__ __launch_bounds__(256) void scatter_k(
    const int* __restrict__ flatE, const int* __restrict__ rankInBlock,
    const int* __restrict__ offTable, float* __restrict__ out_gather) {
  const int i = blockIdx.x * 256 + threadIdx.x;
  const int key = flatE[i];
  const int pos = offTable[key * NB2 + blockIdx.x] + rankInBlock[i];
  out_gather[pos] = (float)i;
}

// ---------------------------------------------------------------------------
extern "C" void kernel_launch(void* const* d_in, const int* in_sizes, int n_in,
                              void* d_out, int out_size, void* d_ws, size_t ws_size,
                              hipStream_t stream) {
  const float* hidden = (const float*)d_in[0];  // [16384, 4096]
  const float* gate   = (const float*)d_in[1];  // [64, 4096]

  float* out        = (float*)d_out;
  float* out_w      = out;              // 32768
  float* out_idx    = out + 32768;      // 32768
  float* out_off    = out + 65536;      // 64
  float* out_gather = out + 65600;      // 32768
  float* out_losses = out + 98368;      // 2

  // workspace layout (~1.4 MB)
  float* gT          = (float*)d_ws;                      // 262144 f32 (1 MB)
  int*   flatE       = (int*)(gT + 262144);               // 32768
  int*   blockCounts = flatE + 32768;                     // 8192
  int*   rankInBlock = blockCounts + 8192;                // 32768
  int*   offTable    = rankInBlock + 32768;               // 8192

  transpose_gate_k<<<1024, 256, 0, stream>>>(gate, gT);
  router_k<<<NTOK / TB, 256, 0, stream>>>(hidden, gT, out_w, out_idx, flatE);
  hist_rank_k<<<NB2, 256, 0, stream>>>(flatE, blockCounts, rankInBlock);
  offsets_k<<<1, 64, 0, stream>>>(blockCounts, offTable, out_off, out_losses);
  scatter_k<<<NB2, 256, 0, stream>>>(flatE, rankInBlock, offTable, out_gather);
}

// Round 2
// 399.674 us; speedup vs baseline: 1.1368x; 1.1368x over previous
//
#include <hip/hip_runtime.h>
#include <hip/hip_bf16.h>
#include <stdint.h>

constexpr int HID  = 4096;
constexpr int NE   = 64;
constexpr int NTOK = 16384;   // 4 * 4096
constexpr int NB2  = 128;     // blocks for sort kernels (32768 / 256)

typedef __attribute__((ext_vector_type(8))) short short8;
typedef __attribute__((ext_vector_type(4))) float f32x4;

union Frag { uint32_t u[4]; short8 s; uint4 q; };

__device__ inline uint32_t cvtpk_bf16(float a, float b) {
  uint32_t r;
  asm("v_cvt_pk_bf16_f32 %0, %1, %2" : "=v"(r) : "v"(a), "v"(b));
  return r;  // r[15:0]=bf16(a), r[31:16]=bf16(b)
}
__device__ inline float asf(uint32_t u) { union { uint32_t u; float f; } c; c.u = u; return c.f; }

// RNE split of 8 f32 into hi/lo bf16x8 fragments: x = hi + lo + O(2^-18 x)
__device__ inline void split8(float4 p, float4 q, Frag& hi, Frag& lo) {
  float x[8] = {p.x, p.y, p.z, p.w, q.x, q.y, q.z, q.w};
#pragma unroll
  for (int j = 0; j < 4; ++j) {
    uint32_t h = cvtpk_bf16(x[2*j], x[2*j+1]);
    hi.u[j] = h;
    float r0 = x[2*j]   - asf(h << 16);
    float r1 = x[2*j+1] - asf(h & 0xFFFF0000u);
    lo.u[j] = cvtpk_bf16(r0, r1);
  }
}

// ---------- kernel 0: gate -> split bf16, MFMA-B-fragment order -------------
// gP uint4 index = ((c*8) + n*2 + part)*64 + l ; c=K-chunk(32), n=N-tile, l=lane
__global__ __launch_bounds__(256) void prep_gate_k(
    const float* __restrict__ gw, uint4* __restrict__ gP) {
  int gid = blockIdx.x * 256 + threadIdx.x;   // 0..65535
  int c = gid >> 9;
  int r = gid & 511;
  int n = r >> 7;
  int part = (r >> 6) & 1;
  int l = r & 63;
  int e  = n * 16 + (l & 15);
  int k0 = c * 32 + (l >> 4) * 8;
  const float* src = gw + (size_t)e * HID + k0;
  float4 p = *(const float4*)src;
  float4 q = *(const float4*)(src + 4);
  Frag hi, lo;
  split8(p, q, hi, lo);
  gP[gid] = part ? lo.q : hi.q;
}

// ---------- kernel 1: MFMA logits GEMM, K-split, no LDS ---------------------
// block = 4 waves, each wave: 32 tokens (2 M-tiles) x 64 experts (4 N-tiles).
// S-way K split; partial[s][t][e] f32.
template <int S>
__global__ __launch_bounds__(256) void gemm_k(
    const float* __restrict__ hidden, const uint4* __restrict__ gP,
    float* __restrict__ partial) {
  constexpr int NCH = 128 / S;            // 32-wide K chunks per block
  const int tid = threadIdx.x;
  const int w = tid >> 6, l = tid & 63;
  const int b = blockIdx.x;
  const int s  = b % S;                   // XCD x serves slice x (b%8 ~ XCD)
  const int tb = b / S;
  const int t0 = tb * 128 + w * 32;
  const int row = l & 15, kg = l >> 4;

  const float* aBase = hidden + (size_t)(t0 + row) * HID + s * (HID / S) + kg * 8;
  const int cG0 = s * NCH;

  f32x4 acc[2][4] = {};
  float4 aC[2][2]; uint4 bC[4][2];

  auto LOAD = [&](int c, float4 (&a)[2][2], uint4 (&bb)[4][2]) {
    const float* ap = aBase + c * 32;
#pragma unroll
    for (int mt = 0; mt < 2; ++mt) {
      const float* p = ap + (size_t)mt * 16 * HID;
      a[mt][0] = *(const float4*)p;
      a[mt][1] = *(const float4*)(p + 4);
    }
    const uint4* bp = gP + (size_t)(cG0 + c) * 512 + l;
#pragma unroll
    for (int nt = 0; nt < 4; ++nt) {
      bb[nt][0] = bp[(nt * 2 + 0) * 64];
      bb[nt][1] = bp[(nt * 2 + 1) * 64];
    }
  };
  auto COMP = [&](float4 (&a)[2][2], uint4 (&bb)[4][2]) {
    Frag ahi[2], alo[2];
#pragma unroll
    for (int mt = 0; mt < 2; ++mt) split8(a[mt][0], a[mt][1], ahi[mt], alo[mt]);
#pragma unroll
    for (int nt = 0; nt < 4; ++nt) {
      Frag bhi, blo; bhi.q = bb[nt][0]; blo.q = bb[nt][1];
#pragma unroll
      for (int mt = 0; mt < 2; ++mt) {
        acc[mt][nt] = __builtin_amdgcn_mfma_f32_16x16x32_bf16(ahi[mt].s, bhi.s, acc[mt][nt], 0, 0, 0);
        acc[mt][nt] = __builtin_amdgcn_mfma_f32_16x16x32_bf16(ahi[mt].s, blo.s, acc[mt][nt], 0, 0, 0);
        acc[mt][nt] = __builtin_amdgcn_mfma_f32_16x16x32_bf16(alo[mt].s, bhi.s, acc[mt][nt], 0, 0, 0);
      }
    }
  };

  LOAD(0, aC, bC);
#pragma unroll 8
  for (int c = 0; c < NCH - 1; ++c) {
    float4 aN[2][2]; uint4 bN[4][2];
    LOAD(c + 1, aN, bN);
    COMP(aC, bC);
#pragma unroll
    for (int mt = 0; mt < 2; ++mt) { aC[mt][0] = aN[mt][0]; aC[mt][1] = aN[mt][1]; }
#pragma unroll
    for (int nt = 0; nt < 4; ++nt) { bC[nt][0] = bN[nt][0]; bC[nt][1] = bN[nt][1]; }
  }
  COMP(aC, bC);

  // store partials: C/D map col=l&15, row=kg*4+r
  float* pout = partial + (size_t)s * NTOK * 64;
#pragma unroll
  for (int mt = 0; mt < 2; ++mt)
#pragma unroll
    for (int r = 0; r < 4; ++r) {
      int t = t0 + mt * 16 + kg * 4 + r;
      float* dst = pout + (size_t)t * 64 + (l & 15);
#pragma unroll
      for (int nt = 0; nt < 4; ++nt) dst[nt * 16] = acc[mt][nt][r];
    }
}

// ---------- kernel 2: reduce partials + softmax + top2 + epilogue -----------
template <int S>
__global__ __launch_bounds__(256) void reduce_router_k(
    const float* __restrict__ partial, float* __restrict__ out_w,
    float* __restrict__ out_idx, int* __restrict__ flatE) {
  const int tid = threadIdx.x;
  const int te = tid & 15, tt = tid >> 4;
  const int t0 = blockIdx.x * 32;

  float acc[2][4] = {{0.f,0.f,0.f,0.f},{0.f,0.f,0.f,0.f}};
#pragma unroll
  for (int i = 0; i < 2; ++i) {
    int t = t0 + 2 * tt + i;
#pragma unroll
    for (int s = 0; s < S; ++s) {
      float4 v = *(const float4*)(partial + ((size_t)s * NTOK + t) * 64 + 4 * te);
      acc[i][0] += v.x; acc[i][1] += v.y; acc[i][2] += v.z; acc[i][3] += v.w;
    }
  }

#pragma unroll
  for (int i = 0; i < 2; ++i) {
    float v1 = -3.0e38f, v2 = -3.0e38f;
    int e1 = 0, e2 = 0;
#pragma unroll
    for (int j = 0; j < 4; ++j) {
      float v = acc[i][j];
      int e = 4 * te + j;
      if (v > v1 || (v == v1 && e < e1)) { v2 = v1; e2 = e1; v1 = v; e1 = e; }
      else if (v > v2 || (v == v2 && e < e2)) { v2 = v; e2 = e; }
    }
#pragma unroll
    for (int m = 1; m <= 8; m <<= 1) {
      float ov1 = __shfl_xor(v1, m); int oe1 = __shfl_xor(e1, m);
      float ov2 = __shfl_xor(v2, m); int oe2 = __shfl_xor(e2, m);
      bool aFirst = (v1 > ov1) || (v1 == ov1 && e1 < oe1);
      float w1v = aFirst ? v1 : ov1;  int w1e = aFirst ? e1 : oe1;
      float c1  = aFirst ? ov1 : v1;  int c1e = aFirst ? oe1 : e1;
      float c2  = aFirst ? v2 : ov2;  int c2e = aFirst ? e2 : oe2;
      bool sset = (c2 > c1) || (c2 == c1 && c2e < c1e);
      v1 = w1v; e1 = w1e;
      v2 = sset ? c2 : c1; e2 = sset ? c2e : c1e;
    }
    float sum = 0.f;
#pragma unroll
    for (int j = 0; j < 4; ++j) sum += __expf(acc[i][j] - v1);
#pragma unroll
    for (int m = 1; m <= 8; m <<= 1) sum += __shfl_xor(sum, m);

    float p1 = 1.0f / sum;
    float p2 = __expf(v2 - v1) / sum;
    float inv = 1.0f / (p1 + p2 + 1e-8f);
    float w1 = p1 * inv, w2 = p2 * inv;

    if (te == 0) {
      int t = t0 + 2 * tt + i;
      out_w[2 * t]       = w1;
      out_w[2 * t + 1]   = w2;
      out_idx[2 * t]     = (float)e1;
      out_idx[2 * t + 1] = (float)e2;
      flatE[2 * t]       = e1;
      flatE[2 * t + 1]   = e2;
    }
  }
}

// ---------- kernel 3a: per-block histogram + stable in-block rank -----------
__global__ __launch_bounds__(256) void hist_rank_k(
    const int* __restrict__ flatE, int* __restrict__ blockCounts,
    int* __restrict__ rankInBlock) {
  __shared__ int waveCnt[4][64];
  const int tid = threadIdx.x, blk = blockIdx.x;
  const int i = blk * 256 + tid;
  const int key = flatE[i];
  const int lane = tid & 63, w = tid >> 6;
  const unsigned long long below = (1ull << lane) - 1ull;

  int rankWave = 0, cntMyLane = 0;
  for (int e = 0; e < 64; ++e) {
    unsigned long long m = __ballot(key == e);
    if (e == key)  rankWave  = __popcll(m & below);
    if (e == lane) cntMyLane = __popcll(m);
  }
  waveCnt[w][lane] = cntMyLane;
  __syncthreads();

  int pre = 0;
  for (int w2 = 0; w2 < w; ++w2) pre += waveCnt[w2][key];
  rankInBlock[i] = pre + rankWave;

  if (tid < 64) {
    int tot = waveCnt[0][tid] + waveCnt[1][tid] + waveCnt[2][tid] + waveCnt[3][tid];
    blockCounts[blk * 64 + tid] = tot;
  }
}

// ---------- kernel 3b: offsets (1 wave) -------------------------------------
__global__ void offsets_k(const int* __restrict__ blockCounts,
                          int* __restrict__ offTable,
                          float* __restrict__ out_off,
                          float* __restrict__ out_losses) {
  const int e = threadIdx.x;  // 0..63
  int run = 0;
  for (int b = 0; b < NB2; ++b) {
    offTable[e * NB2 + b] = run;
    run += blockCounts[b * 64 + e];
  }
  const int total = run;
  int inc = total;
  for (int d = 1; d < 64; d <<= 1) {
    int v = __shfl_up(inc, d);
    if (e >= d) inc += v;
  }
  out_off[e] = (float)inc;
  const int base = inc - total;
  for (int b = 0; b < NB2; ++b) offTable[e * NB2 + b] += base;
  if (e == 0) { out_losses[0] = 0.f; out_losses[1] = 0.f; }
}

// ---------- kernel 3c: stable scatter ---------------------------------------
__global__ __launch_bounds__(256) void scatter_k(
    const int* __restrict__ flatE, const int* __restrict__ rankInBlock,
    const int* __restrict__ offTable, float* __restrict__ out_gather) {
  const int i = blockIdx.x * 256 + threadIdx.x;
  const int key = flatE[i];
  const int pos = offTable[key * NB2 + blockIdx.x] + rankInBlock[i];
  out_gather[pos] = (float)i;
}

// ---------------------------------------------------------------------------
extern "C" void kernel_launch(void* const* d_in, const int* in_sizes, int n_in,
                              void* d_out, int out_size, void* d_ws, size_t ws_size,
                              hipStream_t stream) {
  const float* hidden = (const float*)d_in[0];  // [16384, 4096]
  const float* gate   = (const float*)d_in[1];  // [64, 4096]

  float* out        = (float*)d_out;
  float* out_w      = out;              // 32768
  float* out_idx    = out + 32768;      // 32768
  float* out_off    = out + 65536;      // 64
  float* out_gather = out + 65600;      // 32768
  float* out_losses = out + 98368;      // 2

  // ws: [0,1MB) gP ; [1MB,2MB) sort scratch ; [2MB, ...) partials S*4MB
  uint4* gP          = (uint4*)d_ws;
  int*   flatE       = (int*)((char*)d_ws + (1u << 20));
  int*   blockCounts = flatE + 32768;
  int*   rankInBlock = blockCounts + 8192;
  int*   offTable    = rankInBlock + 32768;
  float* partial     = (float*)((char*)d_ws + (2u << 20));

  const size_t fixed = 2u << 20;
  const size_t perS  = (size_t)NTOK * 64 * 4;   // 4 MB per slice
  int S = 1;
  if      (ws_size >= fixed + 8 * perS) S = 8;
  else if (ws_size >= fixed + 4 * perS) S = 4;
  else if (ws_size >= fixed + 2 * perS) S = 2;

  prep_gate_k<<<256, 256, 0, stream>>>(gate, gP);
  switch (S) {
    case 8:
      gemm_k<8><<<(NTOK / 128) * 8, 256, 0, stream>>>(hidden, gP, partial);
      reduce_router_k<8><<<NTOK / 32, 256, 0, stream>>>(partial, out_w, out_idx, flatE);
      break;
    case 4:
      gemm_k<4><<<(NTOK / 128) * 4, 256, 0, stream>>>(hidden, gP, partial);
      reduce_router_k<4><<<NTOK / 32, 256, 0, stream>>>(partial, out_w, out_idx, flatE);
      break;
    case 2:
      gemm_k<2><<<(NTOK / 128) * 2, 256, 0, stream>>>(hidden, gP, partial);
      reduce_router_k<2><<<NTOK / 32, 256, 0, stream>>>(partial, out_w, out_idx, flatE);
      break;
    default:
      gemm_k<1><<<(NTOK / 128) * 1, 256, 0, stream>>>(hidden, gP, partial);
      reduce_router_k<1><<<NTOK / 32, 256, 0, stream>>>(partial, out_w, out_idx, flatE);
      break;
  }
  hist_rank_k<<<NB2, 256, 0, stream>>>(flatE, blockCounts, rankInBlock);
  offsets_k<<<1, 64, 0, stream>>>(blockCounts, offTable, out_off, out_losses);
  scatter_k<<<NB2, 256, 0, stream>>>(flatE, rankInBlock, offTable, out_gather);
}

// Round 3
// 378.201 us; speedup vs baseline: 1.2013x; 1.0568x over previous
//
#include <hip/hip_runtime.h>
#include <hip/hip_bf16.h>
#include <stdint.h>

constexpr int HID  = 4096;
constexpr int NTOK = 16384;   // 4 * 4096
constexpr int NB2  = 128;     // blocks for sort kernels (32768 / 256)

typedef __attribute__((ext_vector_type(8))) short short8;
typedef __attribute__((ext_vector_type(4))) float f32x4;

union Frag { uint32_t u[4]; short8 s; uint4 q; };

__device__ inline uint32_t cvtpk_bf16(float a, float b) {
  uint32_t r;
  asm("v_cvt_pk_bf16_f32 %0, %1, %2" : "=v"(r) : "v"(a), "v"(b));
  return r;  // r[15:0]=bf16(a), r[31:16]=bf16(b)
}
__device__ inline float asf(uint32_t u) { union { uint32_t u; float f; } c; c.u = u; return c.f; }

// RNE split of 8 f32 into hi/lo bf16x8 fragments: x = hi + lo + O(2^-18 x)
__device__ inline void split8(float4 p, float4 q, Frag& hi, Frag& lo) {
  float x[8] = {p.x, p.y, p.z, p.w, q.x, q.y, q.z, q.w};
#pragma unroll
  for (int j = 0; j < 4; ++j) {
    uint32_t h = cvtpk_bf16(x[2*j], x[2*j+1]);
    hi.u[j] = h;
    float r0 = x[2*j]   - asf(h << 16);
    float r1 = x[2*j+1] - asf(h & 0xFFFF0000u);
    lo.u[j] = cvtpk_bf16(r0, r1);
  }
}

// ---------- kernel 0: gate -> split bf16, MFMA-B-fragment order -------------
// gP uint4 index = (c*8 + n*2 + part)*64 + l ; c=K-chunk(32) 0..127, n=N-tile, l=lane
__global__ __launch_bounds__(256) void prep_gate_k(
    const float* __restrict__ gw, uint4* __restrict__ gP) {
  int gid = blockIdx.x * 256 + threadIdx.x;   // 0..65535
  int c = gid >> 9;
  int r = gid & 511;
  int n = r >> 7;
  int part = (r >> 6) & 1;
  int l = r & 63;
  int e  = n * 16 + (l & 15);
  int k0 = c * 32 + (l >> 4) * 8;
  const float* src = gw + (size_t)e * HID + k0;
  float4 p = *(const float4*)src;
  float4 q = *(const float4*)(src + 4);
  Frag hi, lo;
  split8(p, q, hi, lo);
  gP[gid] = part ? lo.q : hi.q;
}

// ---------- kernel 1: fused MFMA GEMM + wave-K-split reduce + top2 ----------
// 512 thr = 8 waves. Block: 32 tokens x 64 experts, wave w owns K-slice
// [w*512, (w+1)*512) = 16 chunks of 32. Reduce across waves via padded LDS.
__global__ __launch_bounds__(512) void gemm_fused_k(
    const float* __restrict__ hidden, const uint4* __restrict__ gP,
    float* __restrict__ out_w, float* __restrict__ out_idx,
    int* __restrict__ flatE) {
  __shared__ float sm[8][32][68];   // +4 pad: bank-spread + float4-aligned rows

  const int tid = threadIdx.x;
  const int w = tid >> 6, l = tid & 63;
  const int t0 = blockIdx.x * 32;
  const int row = l & 15, kg = l >> 4;

  const float* aBase = hidden + (size_t)(t0 + row) * HID + w * 512 + kg * 8;
  const int c0 = w * 16;

  f32x4 acc[2][4] = {};

  for (int cc = 0; cc < 16; ++cc) {
    const float* ap = aBase + cc * 32;
    float4 a[2][2]; uint4 b[4][2];
#pragma unroll
    for (int mt = 0; mt < 2; ++mt) {
      const float* p = ap + (size_t)mt * 16 * HID;
      a[mt][0] = *(const float4*)p;
      a[mt][1] = *(const float4*)(p + 4);
    }
    const uint4* bp = gP + (size_t)(c0 + cc) * 512 + l;
#pragma unroll
    for (int nt = 0; nt < 4; ++nt) {
      b[nt][0] = bp[(nt * 2 + 0) * 64];
      b[nt][1] = bp[(nt * 2 + 1) * 64];
    }
    Frag ahi[2], alo[2];
#pragma unroll
    for (int mt = 0; mt < 2; ++mt) split8(a[mt][0], a[mt][1], ahi[mt], alo[mt]);
#pragma unroll
    for (int nt = 0; nt < 4; ++nt) {
      Frag bhi, blo; bhi.q = b[nt][0]; blo.q = b[nt][1];
#pragma unroll
      for (int mt = 0; mt < 2; ++mt) {
        acc[mt][nt] = __builtin_amdgcn_mfma_f32_16x16x32_bf16(ahi[mt].s, bhi.s, acc[mt][nt], 0, 0, 0);
        acc[mt][nt] = __builtin_amdgcn_mfma_f32_16x16x32_bf16(ahi[mt].s, blo.s, acc[mt][nt], 0, 0, 0);
        acc[mt][nt] = __builtin_amdgcn_mfma_f32_16x16x32_bf16(alo[mt].s, bhi.s, acc[mt][nt], 0, 0, 0);
      }
    }
  }

  // dump per-wave tile: C/D map col=l&15, row=kg*4+r (verified)
#pragma unroll
  for (int mt = 0; mt < 2; ++mt)
#pragma unroll
    for (int r = 0; r < 4; ++r) {
      int tl = mt * 16 + kg * 4 + r;
#pragma unroll
      for (int nt = 0; nt < 4; ++nt)
        sm[w][tl][nt * 16 + row] = acc[mt][nt][r];
    }
  __syncthreads();

  // ---- cross-wave reduce + softmax + top2: thread = (token tl, expert grp te)
  const int te = tid & 15, tl = tid >> 4;   // tl 0..31
  float av[4] = {0.f, 0.f, 0.f, 0.f};
#pragma unroll
  for (int ww = 0; ww < 8; ++ww) {
    float4 v = *(const float4*)&sm[ww][tl][4 * te];
    av[0] += v.x; av[1] += v.y; av[2] += v.z; av[3] += v.w;
  }

  float v1 = -3.0e38f, v2 = -3.0e38f;
  int e1 = 0, e2 = 0;
#pragma unroll
  for (int j = 0; j < 4; ++j) {
    float v = av[j];
    int e = 4 * te + j;
    if (v > v1 || (v == v1 && e < e1)) { v2 = v1; e2 = e1; v1 = v; e1 = e; }
    else if (v > v2 || (v == v2 && e < e2)) { v2 = v; e2 = e; }
  }
#pragma unroll
  for (int m = 1; m <= 8; m <<= 1) {
    float ov1 = __shfl_xor(v1, m); int oe1 = __shfl_xor(e1, m);
    float ov2 = __shfl_xor(v2, m); int oe2 = __shfl_xor(e2, m);
    bool aFirst = (v1 > ov1) || (v1 == ov1 && e1 < oe1);
    float w1v = aFirst ? v1 : ov1;  int w1e = aFirst ? e1 : oe1;
    float c1  = aFirst ? ov1 : v1;  int c1e = aFirst ? oe1 : e1;
    float c2  = aFirst ? v2 : ov2;  int c2e = aFirst ? e2 : oe2;
    bool sset = (c2 > c1) || (c2 == c1 && c2e < c1e);
    v1 = w1v; e1 = w1e;
    v2 = sset ? c2 : c1; e2 = sset ? c2e : c1e;
  }
  float sum = 0.f;
#pragma unroll
  for (int j = 0; j < 4; ++j) sum += __expf(av[j] - v1);
#pragma unroll
  for (int m = 1; m <= 8; m <<= 1) sum += __shfl_xor(sum, m);

  float p1 = 1.0f / sum;
  float p2 = __expf(v2 - v1) / sum;
  float inv = 1.0f / (p1 + p2 + 1e-8f);
  float w1 = p1 * inv, w2 = p2 * inv;

  if (te == 0) {
    int t = t0 + tl;
    out_w[2 * t]       = w1;
    out_w[2 * t + 1]   = w2;
    out_idx[2 * t]     = (float)e1;
    out_idx[2 * t + 1] = (float)e2;
    flatE[2 * t]       = e1;
    flatE[2 * t + 1]   = e2;
  }
}

// ---------- kernel 2a: per-block histogram + stable in-block rank -----------
__global__ __launch_bounds__(256) void hist_rank_k(
    const int* __restrict__ flatE, int* __restrict__ blockCounts,
    int* __restrict__ rankInBlock) {
  __shared__ int waveCnt[4][64];
  const int tid = threadIdx.x, blk = blockIdx.x;
  const int i = blk * 256 + tid;
  const int key = flatE[i];
  const int lane = tid & 63, w = tid >> 6;
  const unsigned long long below = (1ull << lane) - 1ull;

  int rankWave = 0, cntMyLane = 0;
  for (int e = 0; e < 64; ++e) {
    unsigned long long m = __ballot(key == e);
    if (e == key)  rankWave  = __popcll(m & below);
    if (e == lane) cntMyLane = __popcll(m);
  }
  waveCnt[w][lane] = cntMyLane;
  __syncthreads();

  int pre = 0;
  for (int w2 = 0; w2 < w; ++w2) pre += waveCnt[w2][key];
  rankInBlock[i] = pre + rankWave;

  if (tid < 64) {
    int tot = waveCnt[0][tid] + waveCnt[1][tid] + waveCnt[2][tid] + waveCnt[3][tid];
    blockCounts[blk * 64 + tid] = tot;
  }
}

// ---------- kernel 2b: offsets, hierarchical (1 block, 256 thr) -------------
// offTable layout [b][e] (coalesced stores; scatter reads one row/block)
__global__ __launch_bounds__(256) void offsets_k(
    const int* __restrict__ blockCounts, int* __restrict__ offTable,
    float* __restrict__ out_off, float* __restrict__ out_losses) {
  __shared__ int cnt[4][64];
  __shared__ int baseLds[64];
  const int tid = threadIdx.x;
  const int e = tid & 63, q = tid >> 6;   // q: quarter of the 128 blocks

  int s = 0;
  for (int b = q * 32; b < q * 32 + 32; ++b) s += blockCounts[b * 64 + e];
  cnt[q][e] = s;
  __syncthreads();

  if (tid < 64) {
    int tot = cnt[0][e] + cnt[1][e] + cnt[2][e] + cnt[3][e];
    int inc = tot;
    for (int d = 1; d < 64; d <<= 1) {
      int v = __shfl_up(inc, d);
      if (e >= d) inc += v;
    }
    out_off[e] = (float)inc;          // inclusive cumsum of expert counts
    baseLds[e] = inc - tot;           // exclusive global base
    if (e == 0) { out_losses[0] = 0.f; out_losses[1] = 0.f; }
  }
  __syncthreads();

  int run = baseLds[e];
  for (int q2 = 0; q2 < q; ++q2) run += cnt[q2][e];
  for (int b = q * 32; b < q * 32 + 32; ++b) {
    offTable[b * 64 + e] = run;
    run += blockCounts[b * 64 + e];
  }
}

// ---------- kernel 2c: stable scatter ---------------------------------------
__global__ __launch_bounds__(256) void scatter_k(
    const int* __restrict__ flatE, const int* __restrict__ rankInBlock,
    const int* __restrict__ offTable, float* __restrict__ out_gather) {
  const int i = blockIdx.x * 256 + threadIdx.x;
  const int key = flatE[i];
  const int pos = offTable[blockIdx.x * 64 + key] + rankInBlock[i];
  out_gather[pos] = (float)i;
}

// ---------------------------------------------------------------------------
extern "C" void kernel_launch(void* const* d_in, const int* in_sizes, int n_in,
                              void* d_out, int out_size, void* d_ws, size_t ws_size,
                              hipStream_t stream) {
  const float* hidden = (const float*)d_in[0];  // [16384, 4096]
  const float* gate   = (const float*)d_in[1];  // [64, 4096]

  float* out        = (float*)d_out;
  float* out_w      = out;              // 32768
  float* out_idx    = out + 32768;      // 32768
  float* out_off    = out + 65536;      // 64
  float* out_gather = out + 65600;      // 32768
  float* out_losses = out + 98368;      // 2

  // ws: [0,1MB) gP ; [1MB, ...) sort scratch
  uint4* gP          = (uint4*)d_ws;
  int*   flatE       = (int*)((char*)d_ws + (1u << 20));
  int*   blockCounts = flatE + 32768;
  int*   rankInBlock = blockCounts + 8192;
  int*   offTable    = rankInBlock + 32768;

  prep_gate_k<<<256, 256, 0, stream>>>(gate, gP);
  gemm_fused_k<<<NTOK / 32, 512, 0, stream>>>(hidden, gP, out_w, out_idx, flatE);
  hist_rank_k<<<NB2, 256, 0, stream>>>(flatE, blockCounts, rankInBlock);
  offsets_k<<<1, 256, 0, stream>>>(blockCounts, offTable, out_off, out_losses);
  scatter_k<<<NB2, 256, 0, stream>>>(flatE, rankInBlock, offTable, out_gather);
}